// Round 4
// baseline (497.012 us; speedup 1.0000x reference)
//
#include <hip/hip_runtime.h>
#include <hip/hip_cooperative_groups.h>
#include <math.h>

namespace cg = cooperative_groups;

#define BATCH 4096
#define DIN   2048
#define DOUT  2048
#define DEPTH 16

typedef unsigned short u16;
typedef __attribute__((ext_vector_type(8))) short short8;  // 8 bf16 = 4 VGPRs
typedef __attribute__((ext_vector_type(4))) float f32x4;

// ---------- helpers ----------

__device__ static inline unsigned bf16_rn(float x) {
    unsigned u = __float_as_uint(x);
    return (u + 0x7FFFu + ((u >> 16) & 1u)) >> 16;  // RN-even to bf16 bits
}

__device__ static inline float tanh_fast(float z) {
    float zc = fminf(fmaxf(z, -15.0f), 15.0f);
    float e = __builtin_amdgcn_exp2f(zc * 2.8853900817779268f);  // exp(2z)
    return (e - 1.0f) * __builtin_amdgcn_rcpf(e + 1.0f);
}

__device__ static inline void async16(u16* lds, const u16* g) {
    __builtin_amdgcn_global_load_lds(
        (const __attribute__((address_space(1))) void*)g,
        (__attribute__((address_space(3))) void*)lds, 16, 0, 0);
}

// ---------- fused: prep (split/transpose/probs) + grid.sync + MFMA GEMM ----------
// grid = 512 blocks x 256 thr; 2 blocks/CU co-resident (LDS 32KB, VGPR<=256).
__global__ __launch_bounds__(256, 2) void fused_kernel(
    const float* __restrict__ x,   // [4096, 2048]
    const float* __restrict__ W,   // [16, 2048, 2048]
    const float* __restrict__ cw,  // [2048, 2048]
    const float* __restrict__ cb,  // [2048]
    u16* __restrict__ xh, u16* __restrict__ xl,   // [4096*2048]
    u16* __restrict__ wh, u16* __restrict__ wl,   // [2048*2048] (transposed [n][k])
    float* __restrict__ bp,        // [2048] = bias + probs
    float* __restrict__ C)         // [4096, 2048]
{
    __shared__ u16 smem[16384];  // 32 KB, re-used across phases
    const int tid = threadIdx.x;
    const int bid = blockIdx.x;

    // ---- phase 1a: x -> hi/lo bf16 split (16 float4 per thread) ----
#pragma unroll
    for (int g = 0; g < 16; ++g) {
        int i = (bid * 4096 + g * 256 + tid) * 4;
        float4 v = *(const float4*)(x + i);
        float vv[4] = {v.x, v.y, v.z, v.w};
        u16 hh[4], ll[4];
#pragma unroll
        for (int c = 0; c < 4; ++c) {
            unsigned hb = bf16_rn(vv[c]);
            hh[c] = (u16)hb;
            float r = vv[c] - __uint_as_float(hb << 16);
            ll[c] = (u16)bf16_rn(r);
        }
        ushort4 h, l;
        h.x = hh[0]; h.y = hh[1]; h.z = hh[2]; h.w = hh[3];
        l.x = ll[0]; l.y = ll[1]; l.z = ll[2]; l.w = ll[3];
        *(ushort4*)(xh + i) = h;
        *(ushort4*)(xl + i) = l;
    }

    // ---- phase 1b: W[k][n] -> Wt[n][k] hi/lo (8 tiles of 32x32 per block) ----
    {
        float* t = (float*)smem;  // [32][33]
        const int tx = tid & 31, ty = tid >> 5;  // ty 0..7
#pragma unroll
        for (int it = 0; it < 8; ++it) {
            int tile = bid * 8 + it;
            int n0 = (tile & 63) * 32;
            int k0 = (tile >> 6) * 32;
            __syncthreads();
#pragma unroll
            for (int r = 0; r < 4; ++r)
                t[(ty + r * 8) * 33 + tx] =
                    cw[(size_t)(k0 + ty + r * 8) * DOUT + n0 + tx];
            __syncthreads();
#pragma unroll
            for (int r = 0; r < 4; ++r) {
                float v = t[tx * 33 + ty + r * 8];
                size_t o = (size_t)(n0 + ty + r * 8) * DIN + k0 + tx;
                unsigned hb = bf16_rn(v);
                wh[o] = (u16)hb;
                float rr = v - __uint_as_float(hb << 16);
                wl[o] = (u16)bf16_rn(rr);
            }
        }
    }

    // ---- phase 1c: probs + bias fold (blocks 0..127, 16 j per block) ----
    if (bid < 128) {
        int jl = tid >> 4, d = tid & 15;
        int j = bid * 16 + jl;
        const float* p = W + (size_t)d * DIN * DOUT + (size_t)j * DOUT;
        float pr = cosf(p[0]) * cosf(p[1]) * cosf(p[2]);
#pragma unroll
        for (int off = 1; off < 16; off <<= 1) pr *= __shfl_xor(pr, off, 16);
        if (d == 0) bp[j] = pr * pr * (1.0f / (float)DIN) + cb[j];
    }

    cg::this_grid().sync();

    // ---- phase 2: GEMM C = tanh(x@W + bp), bf16x3, 16x16x32, 128x128 tile ----
    u16* sAh = smem;
    u16* sAl = smem + 4096;
    u16* sBh = smem + 8192;
    u16* sBl = smem + 12288;

    const int lane = tid & 63;
    const int wave = tid >> 6;
    const int bC = (bid & 15) * 128;
    const int bR = (bid >> 4) * 128;

    const u16* gsrc = (wave == 0) ? xh + (size_t)bR * DIN
                    : (wave == 1) ? xl + (size_t)bR * DIN
                    : (wave == 2) ? wh + (size_t)bC * DIN
                                  : wl + (size_t)bC * DIN;
    u16* lbase = (wave == 0) ? sAh : (wave == 1) ? sAl : (wave == 2) ? sBh : sBl;

    int goff[8];
#pragma unroll
    for (int i = 0; i < 8; ++i) {
        int row = i * 16 + (lane >> 2);
        int lq = (lane & 3) ^ ((row >> 1) & 3);  // logical chunk at phys pos lane&3
        goff[i] = row * DIN + lq * 8;
    }

    const int wm = wave >> 1, wn = wave & 1;
    const int colL = lane & 15, quad = lane >> 4;

    int aoff[4], boff[4];
#pragma unroll
    for (int mt = 0; mt < 4; ++mt) {
        int r = wm * 64 + mt * 16 + colL;
        aoff[mt] = r * 32 + (quad ^ ((r >> 1) & 3)) * 8;
    }
#pragma unroll
    for (int nt = 0; nt < 4; ++nt) {
        int r = wn * 64 + nt * 16 + colL;
        boff[nt] = r * 32 + (quad ^ ((r >> 1) & 3)) * 8;
    }

    f32x4 acc[4][4];
#pragma unroll
    for (int mt = 0; mt < 4; ++mt)
#pragma unroll
        for (int nt = 0; nt < 4; ++nt) acc[mt][nt] = (f32x4){0.f, 0.f, 0.f, 0.f};

    for (int k0 = 0; k0 < DIN; k0 += 32) {
        __syncthreads();  // prior frag reads done before overwrite
#pragma unroll
        for (int i = 0; i < 8; ++i)
            async16(lbase + i * 512, gsrc + goff[i] + k0);
        __syncthreads();  // drains vmcnt (m97 structure)

        short8 ah[4], al[4], bh[4], bl[4];
#pragma unroll
        for (int mt = 0; mt < 4; ++mt) {
            ah[mt] = *(const short8*)&sAh[aoff[mt]];
            al[mt] = *(const short8*)&sAl[aoff[mt]];
        }
#pragma unroll
        for (int nt = 0; nt < 4; ++nt) {
            bh[nt] = *(const short8*)&sBh[boff[nt]];
            bl[nt] = *(const short8*)&sBl[boff[nt]];
        }

#pragma unroll
        for (int mt = 0; mt < 4; ++mt)
#pragma unroll
            for (int nt = 0; nt < 4; ++nt) {
                acc[mt][nt] = __builtin_amdgcn_mfma_f32_16x16x32_bf16(
                    ah[mt], bh[nt], acc[mt][nt], 0, 0, 0);
                acc[mt][nt] = __builtin_amdgcn_mfma_f32_16x16x32_bf16(
                    ah[mt], bl[nt], acc[mt][nt], 0, 0, 0);
                acc[mt][nt] = __builtin_amdgcn_mfma_f32_16x16x32_bf16(
                    al[mt], bh[nt], acc[mt][nt], 0, 0, 0);
            }
    }

    // epilogue: C/D map col=lane&15, row=quad*4+reg (verified m89/m91)
    float bpv[4];
#pragma unroll
    for (int nt = 0; nt < 4; ++nt)
        bpv[nt] = bp[bC + wn * 64 + nt * 16 + colL];
#pragma unroll
    for (int mt = 0; mt < 4; ++mt)
#pragma unroll
        for (int nt = 0; nt < 4; ++nt) {
            int c = bC + wn * 64 + nt * 16 + colL;
#pragma unroll
            for (int reg = 0; reg < 4; ++reg) {
                int r = bR + wm * 64 + mt * 16 + quad * 4 + reg;
                C[(size_t)r * DOUT + c] = tanh_fast(acc[mt][nt][reg] + bpv[nt]);
            }
        }
}

extern "C" void kernel_launch(void* const* d_in, const int* in_sizes, int n_in,
                              void* d_out, int out_size, void* d_ws, size_t ws_size,
                              hipStream_t stream) {
    const float* x  = (const float*)d_in[0];
    const float* W  = (const float*)d_in[1];
    const float* cw = (const float*)d_in[2];
    const float* cb = (const float*)d_in[3];
    float* out = (float*)d_out;

    // ws layout: bp f32[2048] | x_hi | x_lo | wt_hi | wt_lo (bf16 bits as u16)
    const size_t PROBS_B = 8192;
    const size_t XSZ = (size_t)BATCH * DIN;
    const size_t WSZ = (size_t)DIN * DOUT;

    float* bp = (float*)d_ws;
    u16* xh = (u16*)((char*)d_ws + PROBS_B);
    u16* xl = xh + XSZ;
    u16* wh = xl + XSZ;
    u16* wl = wh + WSZ;

    void* args[] = {(void*)&x, (void*)&W, (void*)&cw, (void*)&cb,
                    (void*)&xh, (void*)&xl, (void*)&wh, (void*)&wl,
                    (void*)&bp, (void*)&out};
    hipLaunchCooperativeKernel((void*)fused_kernel, dim3(512), dim3(256),
                               args, 0, stream);
}

// Round 5
// 465.974 us; speedup vs baseline: 1.0666x; 1.0666x over previous
//
#include <hip/hip_runtime.h>
#include <math.h>

#define BATCH 4096
#define DIN   2048
#define DOUT  2048
#define DEPTH 16

typedef unsigned short u16;
typedef __attribute__((ext_vector_type(8))) short short8;  // 8 bf16 = 4 VGPRs
typedef __attribute__((ext_vector_type(4))) float f32x4;

// ---------- helpers ----------

__device__ static inline unsigned bf16_rn(float x) {
    unsigned u = __float_as_uint(x);
    return (u + 0x7FFFu + ((u >> 16) & 1u)) >> 16;  // RN-even to bf16 bits
}

__device__ static inline float tanh_fast(float z) {
    float zc = fminf(fmaxf(z, -15.0f), 15.0f);
    float e = __builtin_amdgcn_exp2f(zc * 2.8853900817779268f);  // exp(2z)
    return (e - 1.0f) * __builtin_amdgcn_rcpf(e + 1.0f);
}

__device__ static inline void async16(u16* lds, const u16* g) {
    __builtin_amdgcn_global_load_lds(
        (const __attribute__((address_space(1))) void*)g,
        (__attribute__((address_space(3))) void*)lds, 16, 0, 0);
}

// ---------- probs: probs[j] = (prod cos(W[d,j,g]))^2 / DIN ----------
__global__ __launch_bounds__(256) void probs_kernel(const float* __restrict__ W,
                                                    const float* __restrict__ cb,
                                                    float* __restrict__ bp) {
    int tid = threadIdx.x;
    int jl = tid >> 4, d = tid & 15;
    int j = blockIdx.x * 16 + jl;
    const float* p = W + (size_t)d * DIN * DOUT + (size_t)j * DOUT;
    float pr = cosf(p[0]) * cosf(p[1]) * cosf(p[2]);
#pragma unroll
    for (int off = 1; off < 16; off <<= 1) pr *= __shfl_xor(pr, off, 16);
    if (d == 0) bp[j] = pr * pr * (1.0f / (float)DIN) + cb[j];
}

// ---------- x -> hi/lo bf16 (RN split) ----------
__global__ __launch_bounds__(256) void convert_x_kernel(const float* __restrict__ x,
                                                        u16* __restrict__ xh,
                                                        u16* __restrict__ xl) {
    int i = (blockIdx.x * 256 + threadIdx.x) * 4;
    float4 v = *(const float4*)(x + i);
    float vv[4] = {v.x, v.y, v.z, v.w};
    u16 hh[4], ll[4];
#pragma unroll
    for (int c = 0; c < 4; ++c) {
        unsigned hb = bf16_rn(vv[c]);
        hh[c] = (u16)hb;
        float r = vv[c] - __uint_as_float(hb << 16);
        ll[c] = (u16)bf16_rn(r);
    }
    ushort4 h, l;
    h.x = hh[0]; h.y = hh[1]; h.z = hh[2]; h.w = hh[3];
    l.x = ll[0]; l.y = ll[1]; l.z = ll[2]; l.w = ll[3];
    *(ushort4*)(xh + i) = h;
    *(ushort4*)(xl + i) = l;
}

// ---------- W[k][n] -> Wt_hi/Wt_lo[n][k] (transpose + RN split) ----------
__global__ __launch_bounds__(256) void transpose_w_kernel(const float* __restrict__ W,
                                                          u16* __restrict__ wh,
                                                          u16* __restrict__ wl) {
    __shared__ float t[32][33];
    int n0 = blockIdx.x * 32, k0 = blockIdx.y * 32;
    int tx = threadIdx.x & 31, ty = threadIdx.x >> 5;  // ty 0..7
#pragma unroll
    for (int i = 0; i < 4; ++i)
        t[ty + i * 8][tx] = W[(size_t)(k0 + ty + i * 8) * DOUT + n0 + tx];
    __syncthreads();
#pragma unroll
    for (int i = 0; i < 4; ++i) {
        float v = t[tx][ty + i * 8];
        size_t o = (size_t)(n0 + ty + i * 8) * DIN + k0 + tx;
        unsigned hb = bf16_rn(v);
        wh[o] = (u16)hb;
        float r = v - __uint_as_float(hb << 16);
        wl[o] = (u16)bf16_rn(r);
    }
}

// ---------- MFMA GEMM: C = tanh(x@W + bp), bf16x3, 16x16x32 ----------
// 128x64 block tile -> grid 1024 = 4 blocks/CU (occupancy lever, r4 showed
// 2 blocks/CU leaves MfmaUtil at 22% from barrier-drain starvation).
// LDS 24KB: sAh/sAl 128x32, sBh/sBl 64x32. Waves 2x2; wave tile 64x32 (4x2).
__global__ __launch_bounds__(256, 4) void gemm_mfma_kernel(
    const u16* __restrict__ xh, const u16* __restrict__ xl,
    const u16* __restrict__ wh, const u16* __restrict__ wl,
    const float* __restrict__ bp, float* __restrict__ C)
{
    __shared__ u16 sAh[4096];
    __shared__ u16 sAl[4096];
    __shared__ u16 sBh[2048];
    __shared__ u16 sBl[2048];

    const int tid = threadIdx.x;
    const int lane = tid & 63;
    const int wave = tid >> 6;
    const int bR = blockIdx.y * 128;
    const int bC = blockIdx.x * 64;

    // Wave->array staging: A limbs 8x1KB chunks, B limbs 4x1KB chunks.
    const u16* gsrc = (wave == 0) ? xh + (size_t)bR * DIN
                    : (wave == 1) ? xl + (size_t)bR * DIN
                    : (wave == 2) ? wh + (size_t)bC * DIN
                                  : wl + (size_t)bC * DIN;
    u16* lbase = (wave == 0) ? sAh : (wave == 1) ? sAl : (wave == 2) ? sBh : sBl;
    const int nchunk = (wave < 2) ? 8 : 4;

    int goff[8];
#pragma unroll
    for (int i = 0; i < 8; ++i) {
        int row = i * 16 + (lane >> 2);
        int lq = (lane & 3) ^ ((row >> 1) & 3);  // logical chunk at phys pos lane&3
        goff[i] = row * DIN + lq * 8;
    }

    const int wm = wave >> 1, wn = wave & 1;
    const int colL = lane & 15, quad = lane >> 4;

    int aoff[4], boff[2];
#pragma unroll
    for (int mt = 0; mt < 4; ++mt) {
        int r = wm * 64 + mt * 16 + colL;
        aoff[mt] = r * 32 + (quad ^ ((r >> 1) & 3)) * 8;
    }
#pragma unroll
    for (int nt = 0; nt < 2; ++nt) {
        int r = wn * 32 + nt * 16 + colL;
        boff[nt] = r * 32 + (quad ^ ((r >> 1) & 3)) * 8;
    }

    f32x4 acc[4][2];
#pragma unroll
    for (int mt = 0; mt < 4; ++mt)
#pragma unroll
        for (int nt = 0; nt < 2; ++nt) acc[mt][nt] = (f32x4){0.f, 0.f, 0.f, 0.f};

    for (int k0 = 0; k0 < DIN; k0 += 32) {
        __syncthreads();  // prior frag reads done before overwrite
#pragma unroll
        for (int i = 0; i < 8; ++i)
            if (i < nchunk) async16(lbase + i * 512, gsrc + goff[i] + k0);
        __syncthreads();  // drains vmcnt before barrier (m97 structure)

        short8 ah[4], al[4], bh[2], bl[2];
#pragma unroll
        for (int mt = 0; mt < 4; ++mt) {
            ah[mt] = *(const short8*)&sAh[aoff[mt]];
            al[mt] = *(const short8*)&sAl[aoff[mt]];
        }
#pragma unroll
        for (int nt = 0; nt < 2; ++nt) {
            bh[nt] = *(const short8*)&sBh[boff[nt]];
            bl[nt] = *(const short8*)&sBl[boff[nt]];
        }

#pragma unroll
        for (int mt = 0; mt < 4; ++mt)
#pragma unroll
            for (int nt = 0; nt < 2; ++nt) {
                acc[mt][nt] = __builtin_amdgcn_mfma_f32_16x16x32_bf16(
                    ah[mt], bh[nt], acc[mt][nt], 0, 0, 0);
                acc[mt][nt] = __builtin_amdgcn_mfma_f32_16x16x32_bf16(
                    ah[mt], bl[nt], acc[mt][nt], 0, 0, 0);
                acc[mt][nt] = __builtin_amdgcn_mfma_f32_16x16x32_bf16(
                    al[mt], bh[nt], acc[mt][nt], 0, 0, 0);
            }
    }

    // epilogue: C/D map col=lane&15, row=quad*4+reg (verified m89/m91)
    float bpv[2];
#pragma unroll
    for (int nt = 0; nt < 2; ++nt)
        bpv[nt] = bp[bC + wn * 32 + nt * 16 + colL];
#pragma unroll
    for (int mt = 0; mt < 4; ++mt)
#pragma unroll
        for (int nt = 0; nt < 2; ++nt) {
            int c = bC + wn * 32 + nt * 16 + colL;
#pragma unroll
            for (int reg = 0; reg < 4; ++reg) {
                int r = bR + wm * 64 + mt * 16 + quad * 4 + reg;
                C[(size_t)r * DOUT + c] = tanh_fast(acc[mt][nt][reg] + bpv[nt]);
            }
        }
}

extern "C" void kernel_launch(void* const* d_in, const int* in_sizes, int n_in,
                              void* d_out, int out_size, void* d_ws, size_t ws_size,
                              hipStream_t stream) {
    const float* x  = (const float*)d_in[0];  // [4096, 2048]
    const float* W  = (const float*)d_in[1];  // [16, 2048, 2048]
    const float* cw = (const float*)d_in[2];  // [2048, 2048]
    const float* cb = (const float*)d_in[3];  // [2048]
    float* out = (float*)d_out;

    // ws layout: bp f32[2048] | x_hi | x_lo | wt_hi | wt_lo (bf16 bits as u16)
    const size_t PROBS_B = 8192;
    const size_t XSZ = (size_t)BATCH * DIN;
    const size_t WSZ = (size_t)DIN * DOUT;

    float* bp = (float*)d_ws;
    u16* xh = (u16*)((char*)d_ws + PROBS_B);
    u16* xl = xh + XSZ;
    u16* wh = xl + XSZ;
    u16* wl = wh + WSZ;

    probs_kernel<<<DOUT / 16, 256, 0, stream>>>(W, cb, bp);
    convert_x_kernel<<<XSZ / 4 / 256, 256, 0, stream>>>(x, xh, xl);
    transpose_w_kernel<<<dim3(DOUT / 32, DIN / 32), 256, 0, stream>>>(cw, wh, wl);

    dim3 grid(DOUT / 64, BATCH / 128);
    gemm_mfma_kernel<<<grid, 256, 0, stream>>>(xh, xl, wh, wl, bp, out);
}